// Round 4
// baseline (580.679 us; speedup 1.0000x reference)
//
#include <hip/hip_runtime.h>
#include <stdint.h>

#define NVERT 100000
#define NEDGE 50000
#define DIM 128
#define NNZ_N 1600000
#define N4 (NNZ_N / 4)
#define CAP_E 96                 // fixed-capacity e-buckets; Poisson(32) tail @96 ~ 1e-18
#define NB_QTR 1563              // ceil(N4/256) = ceil(NVERT/64)
#define LDS_STRIDE 136           // 128 + 8 bf16 pad -> 2-way-free ds_read_b128

typedef __attribute__((ext_vector_type(8))) short bf16x8;
typedef __attribute__((ext_vector_type(4))) float f32x4;

__device__ __forceinline__ unsigned short f32_to_bf16(float f) {
  union { float f; unsigned u; } v; v.f = f;
  unsigned r = v.u + 0x7fffu + ((v.u >> 16) & 1u);
  return (unsigned short)(r >> 16);
}
__device__ __forceinline__ float bf16_lo(unsigned u) {
  union { unsigned u; float f; } v; v.u = u << 16; return v.f;
}
__device__ __forceinline__ float bf16_hi(unsigned u) {
  union { unsigned u; float f; } v; v.u = u & 0xffff0000u; return v.f;
}
// dual-dtype load of external "float" inputs (f32 or bf16, runtime flag)
__device__ __forceinline__ float ldf(const void* p, long i, int bf) {
  if (bf) {
    union { unsigned u; float f; } v;
    v.u = (unsigned)((const unsigned short*)p)[i] << 16;
    return v.f;
  }
  return ((const float*)p)[i];
}
// 8-elem bf16 MFMA fragment from external (flag) array at element idx
__device__ __forceinline__ bf16x8 frag_ext(const void* A, long idx, int bf) {
  if (bf) return *(const bf16x8*)((const unsigned short*)A + idx);
  const float* f = (const float*)A + idx;
  float4 f0 = *(const float4*)f, f1 = *(const float4*)(f + 4);
  bf16x8 r;
  r[0] = (short)f32_to_bf16(f0.x); r[1] = (short)f32_to_bf16(f0.y);
  r[2] = (short)f32_to_bf16(f0.z); r[3] = (short)f32_to_bf16(f0.w);
  r[4] = (short)f32_to_bf16(f1.x); r[5] = (short)f32_to_bf16(f1.y);
  r[6] = (short)f32_to_bf16(f1.z); r[7] = (short)f32_to_bf16(f1.w);
  return r;
}

// per-block dtype detect (1024 samples of even-index u16 exponents)
__device__ __forceinline__ int block_flag(const unsigned short* x) {
  __shared__ int cnt;
  if (threadIdx.x == 0) cnt = 0;
  __syncthreads();
  int c = 0;
#pragma unroll
  for (int k = 0; k < 4; ++k) {
    unsigned short h = x[(threadIdx.x * 4 + k) * 2];
    int ex = (h >> 7) & 0xFF;
    c += (ex >= 100 && ex <= 140) ? 1 : 0;
  }
  atomicAdd(&cnt, c);
  __syncthreads();
  return cnt > 512;
}

// ---- weight/bias prep + counter zeroing in one launch (907 blocks) ----
__global__ __launch_bounds__(256) void prep_all(
    const unsigned short* __restrict__ Xu,
    const void* __restrict__ btv, const void* __restrict__ bvm,
    const void* __restrict__ Wtv, const void* __restrict__ Wvm,
    const void* __restrict__ Wte, const void* __restrict__ Wem,
    const void* __restrict__ bte, const void* __restrict__ bem,
    float* __restrict__ btvf, float* __restrict__ bvmf, float* __restrict__ bcf,
    unsigned short* __restrict__ Wtvb, unsigned short* __restrict__ Wvmb,
    unsigned short* __restrict__ Wcb, int* __restrict__ flag,
    int* __restrict__ cnt_e, int* __restrict__ cnt_v) {
  int b = blockIdx.x, t = threadIdx.x;
  if (b >= 321) {                            // zero cnt_e (50000) + cnt_v (100000)
    int i = (b - 321) * 256 + t;
    if (i < NEDGE) cnt_e[i] = 0;
    else if (i < NEDGE + NVERT) cnt_v[i - NEDGE] = 0;
    return;
  }
  int bf = block_flag(Xu);
  if (b == 0) {
    if (t == 0) flag[0] = bf;
    if (t < 128) btvf[t] = ldf(btv, t, bf);
    else bvmf[t - 128] = ldf(bvm, t - 128, bf);
  } else if (b < 65) {                       // W_tv: 16384 elems
    int i = (b - 1) * 256 + t;
    Wtvb[i] = f32_to_bf16(ldf(Wtv, i, bf));
  } else if (b < 193) {                      // W_vm: 32768 elems
    int i = (b - 65) * 256 + t;
    Wvmb[i] = f32_to_bf16(ldf(Wvm, i, bf));
  } else {                                   // fused Wc = Wte @ Wem, bc
    int n = b - 193, k = t;
    float acc = 0.f;
    for (int j = 0; j < 128; ++j)
      acc += ldf(Wte, n * 128 + j, bf) * ldf(Wem, j * 256 + k, bf);
    Wcb[n * 256 + k] = f32_to_bf16(acc);
    if (k == 0) {
      float bb = ldf(bte, n, bf);
      for (int j = 0; j < 128; ++j) bb += ldf(Wte, n * 128 + j, bf) * ldf(bem, j, bf);
      bcf[n] = bb;
    }
  }
}

// ---------- CSR build bodies (split e / v for pipeline overlap) ----------
// e-side: fixed-cap direct scatter (returning atomic IS the slot).
__device__ __forceinline__ void ecount_body(
    const int4* __restrict__ vi, const int4* __restrict__ ei,
    int* __restrict__ cnt_e, int* __restrict__ adj_e, int bid) {
  int i = bid * 256 + threadIdx.x;
  if (i >= N4) return;
  int4 e = ei[i], v = vi[i];
  int t;
  t = atomicAdd(&cnt_e[e.x], 1); if (t < CAP_E) adj_e[e.x * CAP_E + t] = v.x;
  t = atomicAdd(&cnt_e[e.y], 1); if (t < CAP_E) adj_e[e.y * CAP_E + t] = v.y;
  t = atomicAdd(&cnt_e[e.z], 1); if (t < CAP_E) adj_e[e.z * CAP_E + t] = v.z;
  t = atomicAdd(&cnt_e[e.w], 1); if (t < CAP_E) adj_e[e.w * CAP_E + t] = v.w;
}

// v-side: returning atomic -> ticket stored coalesced (exact CSR after scan).
__device__ __forceinline__ void vcount_body(
    const int4* __restrict__ vi, int* __restrict__ cnt_v,
    int4* __restrict__ tV, int bid) {
  int i = bid * 256 + threadIdx.x;
  if (i >= N4) return;
  int4 v = vi[i];
  int4 tv;
  tv.x = atomicAdd(&cnt_v[v.x], 1);
  tv.y = atomicAdd(&cnt_v[v.y], 1);
  tv.z = atomicAdd(&cnt_v[v.z], 1);
  tv.w = atomicAdd(&cnt_v[v.w], 1);
  tV[i] = tv;
}

// final position = partial_off + bsum + ticket (scan_add folded in here)
__global__ __launch_bounds__(256) void k_wadjv(
    const int4* __restrict__ vi, const int4* __restrict__ ei,
    const int4* __restrict__ tV, const int* __restrict__ off_v,
    const int* __restrict__ bsum, int* __restrict__ adj_v) {
  int i = blockIdx.x * 256 + threadIdx.x;
  if (i >= N4) return;
  int4 e = ei[i], v = vi[i], tv = tV[i];
  adj_v[off_v[v.x] + bsum[v.x >> 10] + tv.x] = e.x;
  adj_v[off_v[v.y] + bsum[v.y >> 10] + tv.y] = e.y;
  adj_v[off_v[v.z] + bsum[v.z >> 10] + tv.z] = e.z;
  adj_v[off_v[v.w] + bsum[v.w >> 10] + tv.w] = e.w;
}

// ---------- scans (v-side only; add folded into consumers) ----------
__global__ __launch_bounds__(1024) void scan_block(const int* __restrict__ in,
                                                   int* __restrict__ out,
                                                   int* __restrict__ bsum, int n) {
  __shared__ int sd[1024];
  const int tid = threadIdx.x;
  const int i = blockIdx.x * 1024 + tid;
  int x = (i < n) ? in[i] : 0;
  sd[tid] = x;
  __syncthreads();
  int v = x;
  for (int s = 1; s < 1024; s <<= 1) {
    int t = (tid >= s) ? sd[tid - s] : 0;
    __syncthreads();
    v += t;
    sd[tid] = v;
    __syncthreads();
  }
  if (i < n) out[i] = v - x;
  if (tid == 1023) bsum[blockIdx.x] = v;
}

__global__ __launch_bounds__(1024) void scan_sums(int* __restrict__ bsum, int nb) {
  __shared__ int sd[1024];
  const int tid = threadIdx.x;
  int x = (tid < nb) ? bsum[tid] : 0;
  sd[tid] = x;
  __syncthreads();
  int v = x;
  for (int s = 1; s < 1024; s <<= 1) {
    int t = (tid >= s) ? sd[tid - s] : 0;
    __syncthreads();
    v += t;
    sd[tid] = v;
    __syncthreads();
  }
  if (tid < nb) bsum[tid] = v - x;
}

// ---------- seg-mean -> LDS (bf16, padded): 64 rows per block, 4 rounds x 16 groups ----
// CAPMODE: segments at fixed stride CAP_E, length cnt[seg].
// else: CSR offsets = off[seg] + bsum[seg>>10], tail = total.
template<bool CAPMODE>
__device__ __forceinline__ void seg_to_lds(
    const int* __restrict__ off_or_cnt, const int* __restrict__ bsum, int total,
    const int* __restrict__ adj, const unsigned short* __restrict__ tbl,
    unsigned short* __restrict__ lds, int nseg, int nrows, int blk) {
  const int g = threadIdx.x >> 4;   // group 0..15 -> one segment per round
  const int l = threadIdx.x & 15;   // lane in group -> cols l*8..l*8+7
#pragma unroll
  for (int t = 0; t < 4; ++t) {
    const int seg_local = t * 16 + g;
    const int seg = blk * 64 + seg_local;
    if (seg < nseg) {
      int s, e, cnt;
      if (CAPMODE) {
        cnt = off_or_cnt[seg];
        s = seg * CAP_E;
        e = s + (cnt < CAP_E ? cnt : CAP_E);
      } else {
        s = off_or_cnt[seg] + bsum[seg >> 10];
        e = (seg + 1 < nseg) ? off_or_cnt[seg + 1] + bsum[(seg + 1) >> 10] : total;
        cnt = e - s;
      }
      float a0 = 0, a1 = 0, a2 = 0, a3 = 0, a4 = 0, a5 = 0, a6 = 0, a7 = 0;
#define ACC(u)                                         \
  a0 += bf16_lo(u.x); a1 += bf16_hi(u.x);              \
  a2 += bf16_lo(u.y); a3 += bf16_hi(u.y);              \
  a4 += bf16_lo(u.z); a5 += bf16_hi(u.z);              \
  a6 += bf16_lo(u.w); a7 += bf16_hi(u.w);
      int i = s;
      for (; i + 4 <= e; i += 4) {
        int r0 = adj[i], r1 = adj[i + 1], r2 = adj[i + 2], r3 = adj[i + 3];
        if ((unsigned)r0 >= (unsigned)nrows) r0 = 0;
        if ((unsigned)r1 >= (unsigned)nrows) r1 = 0;
        if ((unsigned)r2 >= (unsigned)nrows) r2 = 0;
        if ((unsigned)r3 >= (unsigned)nrows) r3 = 0;
        uint4 u0 = *(const uint4*)(tbl + (long)r0 * DIM + l * 8);
        uint4 u1 = *(const uint4*)(tbl + (long)r1 * DIM + l * 8);
        uint4 u2 = *(const uint4*)(tbl + (long)r2 * DIM + l * 8);
        uint4 u3 = *(const uint4*)(tbl + (long)r3 * DIM + l * 8);
        ACC(u0) ACC(u1) ACC(u2) ACC(u3)
      }
      for (; i < e; ++i) {
        int r = adj[i];
        if ((unsigned)r >= (unsigned)nrows) r = 0;
        uint4 u = *(const uint4*)(tbl + (long)r * DIM + l * 8);
        ACC(u)
      }
#undef ACC
      float inv = (cnt > 0) ? 1.f / (float)cnt : 0.f;
      bf16x8 r;
      r[0] = (short)f32_to_bf16(a0 * inv); r[1] = (short)f32_to_bf16(a1 * inv);
      r[2] = (short)f32_to_bf16(a2 * inv); r[3] = (short)f32_to_bf16(a3 * inv);
      r[4] = (short)f32_to_bf16(a4 * inv); r[5] = (short)f32_to_bf16(a5 * inv);
      r[6] = (short)f32_to_bf16(a6 * inv); r[7] = (short)f32_to_bf16(a7 * inv);
      *(bf16x8*)&lds[seg_local * LDS_STRIDE + l * 8] = r;
    }
  }
  __syncthreads();
}

// ---------- MFMA GEMM bodies ----------
// plain: out[M][128] = A[M][K] @ B[128][K]^T + bias (K=128 external only)
template<int KSTEPS, bool STORE_BF16>
__device__ __forceinline__ void gemm_body(
    int bid, const void* __restrict__ A0,
    const unsigned short* __restrict__ Bw, const float* __restrict__ biasf,
    unsigned short* __restrict__ outb, int M, int bf) {
  constexpr int K = KSTEPS * 32;
  const int wave = threadIdx.x >> 6;
  const int lane = threadIdx.x & 63;
  const int m0 = bid * 64 + wave * 16;
  if (m0 >= M) return;              // M % 16 == 0 -> wave-level cull is exact
  const int c = lane & 15;          // A row in strip / out col in tile
  const int q = lane >> 4;          // k-chunk selector; C/D row group
  const long arow = m0 + c;

  f32x4 acc[8];
#pragma unroll
  for (int t = 0; t < 8; ++t) acc[t] = (f32x4){0.f, 0.f, 0.f, 0.f};
#pragma unroll
  for (int ks = 0; ks < KSTEPS; ++ks) {
    const int kk = ks * 32 + q * 8;
    bf16x8 a = frag_ext(A0, arow * (long)K + kk, bf);
#pragma unroll
    for (int t = 0; t < 8; ++t) {
      bf16x8 b = *(const bf16x8*)(Bw + (long)(t * 16 + c) * K + kk);
      acc[t] = __builtin_amdgcn_mfma_f32_16x16x32_bf16(a, b, acc[t], 0, 0, 0);
    }
  }
  // C/D layout [m89-verified]: col = t*16 + c, row = m0 + q*4 + reg
#pragma unroll
  for (int t = 0; t < 8; ++t) {
    float bv = biasf[t * 16 + c];
#pragma unroll
    for (int i = 0; i < 4; ++i) acc[t][i] += bv;
  }
  if (STORE_BF16) {
#pragma unroll
    for (int t = 0; t < 8; ++t) {
      int col = t * 16 + c;
#pragma unroll
      for (int i = 0; i < 4; ++i)
        outb[(long)(m0 + q * 4 + i) * DIM + col] = f32_to_bf16(acc[t][i]);
    }
  }
}

// K=256 split: k<128 from external A0, k>=128 from LDS (bf16 msg rows) + LN epilogue
template<bool STORE_BF16>
__device__ __forceinline__ void gemm_lds_body(
    int bid, const void* __restrict__ A0, const unsigned short* __restrict__ lds,
    const unsigned short* __restrict__ Bw, const float* __restrict__ biasf,
    unsigned short* __restrict__ outb, float* __restrict__ outf,
    const void* __restrict__ gw_, const void* __restrict__ bw_,
    int M, int bf) {
  constexpr int K = 256;
  const int wave = threadIdx.x >> 6;
  const int lane = threadIdx.x & 63;
  const int m0 = bid * 64 + wave * 16;
  if (m0 >= M) return;
  const int c = lane & 15;
  const int q = lane >> 4;
  const long arow = m0 + c;
  const int rloc = wave * 16 + c;   // LDS row for this lane's A fragment

  f32x4 acc[8];
#pragma unroll
  for (int t = 0; t < 8; ++t) acc[t] = (f32x4){0.f, 0.f, 0.f, 0.f};
#pragma unroll
  for (int ks = 0; ks < 8; ++ks) {
    const int kk = ks * 32 + q * 8;
    bf16x8 a;
    if (ks >= 4) a = *(const bf16x8*)&lds[rloc * LDS_STRIDE + (kk - 128)];
    else         a = frag_ext(A0, arow * 128 + kk, bf);
#pragma unroll
    for (int t = 0; t < 8; ++t) {
      bf16x8 b = *(const bf16x8*)(Bw + (long)(t * 16 + c) * K + kk);
      acc[t] = __builtin_amdgcn_mfma_f32_16x16x32_bf16(a, b, acc[t], 0, 0, 0);
    }
  }
#pragma unroll
  for (int t = 0; t < 8; ++t) {
    float bv = biasf[t * 16 + c];
#pragma unroll
    for (int i = 0; i < 4; ++i) acc[t][i] += bv;
  }
  if (STORE_BF16) {
#pragma unroll
    for (int t = 0; t < 8; ++t) {
      int col = t * 16 + c;
#pragma unroll
      for (int i = 0; i < 4; ++i)
        outb[(long)(m0 + q * 4 + i) * DIM + col] = f32_to_bf16(acc[t][i]);
    }
  }
  // LN + relu epilogue
  float sum[4] = {0, 0, 0, 0}, sq[4] = {0, 0, 0, 0};
#pragma unroll
  for (int t = 0; t < 8; ++t)
#pragma unroll
    for (int i = 0; i < 4; ++i) { float v = acc[t][i]; sum[i] += v; sq[i] += v * v; }
#pragma unroll
  for (int m = 1; m <= 8; m <<= 1) {
#pragma unroll
    for (int i = 0; i < 4; ++i) {
      sum[i] += __shfl_xor(sum[i], m, 64);
      sq[i]  += __shfl_xor(sq[i], m, 64);
    }
  }
  float mean[4], rstd[4];
#pragma unroll
  for (int i = 0; i < 4; ++i) {
    mean[i] = sum[i] * (1.0f / 128.0f);
    float var = sq[i] * (1.0f / 128.0f) - mean[i] * mean[i];
    rstd[i] = rsqrtf(var + 1e-5f);
  }
#pragma unroll
  for (int t = 0; t < 8; ++t) {
    int col = t * 16 + c;
    float gv = ldf(gw_, col, bf), bv = ldf(bw_, col, bf);
#pragma unroll
    for (int i = 0; i < 4; ++i) {
      float v = (acc[t][i] - mean[i]) * rstd[i] * gv + bv;
      v = v > 0.f ? v : 0.f;
      outf[(long)(m0 + q * 4 + i) * DIM + col] = v;
    }
  }
}

// ---------- fused heterogeneous launches ----------
// K1: even -> e-count scatter (atomic-bound) ; odd -> gemm1 (Xp = X @ W_tv^T)
__global__ __launch_bounds__(256) void k_ecount_gemm1(
    const int4* __restrict__ vi, const int4* __restrict__ ei,
    int* __restrict__ cnt_e, int* __restrict__ adj_e,
    const void* __restrict__ X, const unsigned short* __restrict__ Wtvb,
    const float* __restrict__ btvf, unsigned short* __restrict__ Xp_b,
    const int* __restrict__ flagp) {
  if (blockIdx.x & 1)
    gemm_body<4, true>(blockIdx.x >> 1, X, Wtvb, btvf, Xp_b, NVERT, *flagp);
  else
    ecount_body(vi, ei, cnt_e, adj_e, blockIdx.x >> 1);
}

// K2: %3<2 -> v-count tickets (atomic-bound) ; %3==2 -> fused seg1->LDS->gemm2+LN
__global__ __launch_bounds__(256) void k_vcount_seg1gemm2(
    const int4* __restrict__ vi, int* __restrict__ cnt_v, int4* __restrict__ tV,
    const int* __restrict__ cnt_e, const int* __restrict__ adj_e,
    const unsigned short* __restrict__ Xp_b,
    const void* __restrict__ Y, const unsigned short* __restrict__ Wcb,
    const float* __restrict__ bcf, unsigned short* __restrict__ Ym_b,
    float* __restrict__ Yo, const void* __restrict__ g_e,
    const void* __restrict__ be_e, const int* __restrict__ flagp) {
  __shared__ unsigned short lds[64 * LDS_STRIDE];
  int r = blockIdx.x % 3, q = blockIdx.x / 3;
  if (r < 2) {
    vcount_body(vi, cnt_v, tV, q * 2 + r);
    return;
  }
  seg_to_lds<true>(cnt_e, nullptr, 0, adj_e, Xp_b, lds, NEDGE, NVERT, q);
  gemm_lds_body<true>(q, Y, lds, Wcb, bcf, Ym_b, Yo, g_e, be_e, NEDGE, *flagp);
}

// K4: fused seg2->LDS->gemm3+LN (Xo = relu(LN(concat(X, msg_v) @ W_vm^T + b_vm)))
__global__ __launch_bounds__(256) void k_seg2gemm3(
    const int* __restrict__ off_v, const int* __restrict__ bsum,
    const int* __restrict__ adj_v, const unsigned short* __restrict__ Ym_b,
    const void* __restrict__ X, const unsigned short* __restrict__ Wvmb,
    const float* __restrict__ bvmf, float* __restrict__ Xo,
    const void* __restrict__ g_v, const void* __restrict__ be_v,
    const int* __restrict__ flagp) {
  __shared__ unsigned short lds[64 * LDS_STRIDE];
  seg_to_lds<false>(off_v, bsum, NNZ_N, adj_v, Ym_b, lds, NVERT, NEDGE, blockIdx.x);
  gemm_lds_body<false>(blockIdx.x, X, lds, Wvmb, bvmf, nullptr, Xo, g_v, be_v,
                       NVERT, *flagp);
}

extern "C" void kernel_launch(void* const* d_in, const int* in_sizes, int n_in,
                              void* d_out, int out_size, void* d_ws, size_t ws_size,
                              hipStream_t stream) {
  const void* X    = d_in[0];
  const void* Y    = d_in[1];
  const int*  v_idx = (const int*)d_in[2];
  const int*  e_idx = (const int*)d_in[3];
  const void* W_tv = d_in[4];
  const void* b_tv = d_in[5];
  const void* W_te = d_in[6];
  const void* b_te = d_in[7];
  const void* W_em = d_in[8];
  const void* b_em = d_in[9];
  const void* W_vm = d_in[10];
  const void* b_vm = d_in[11];
  const void* g_v  = d_in[12];
  const void* be_v = d_in[13];
  const void* g_e  = d_in[14];
  const void* be_e = d_in[15];

  // d_out (76.8 MB) liveness packing:
  //  K1:  adj_e[25.6M,44.8M) cap-96 buckets ; Xp_b(bf16) [0,25.6M)
  //  K2:  tV tickets [44.8M,51.2M) ; Yo(f32) [51.2M,76.8M)  (msg_e lives in LDS only)
  //  K3:  adj_v in ws (reads tV)
  //  K4:  Xo(f32) [0,51.2M) over dead Xp/adj_e/tV (msg_v lives in LDS only)
  unsigned short* Xp_b = (unsigned short*)d_out;
  int*   adj_e = (int*)((char*)d_out + 25600000);   // 50000*96*4 = 19.2 MB
  int4*  tV4   = (int4*)((char*)d_out + 44800000);  // 1.6M ints = 6.4 MB
  float* Yo    = (float*)d_out + (long)NVERT * DIM;
  float* Xo    = (float*)d_out;

  // ws ~20.5 MB
  char* p = (char*)d_ws;
  auto alloc = [&](size_t n) { char* r = p; p += (n + 255) & ~(size_t)255; return r; };
  int*   flag  = (int*)alloc(4);
  float* btv_f = (float*)alloc(DIM * 4);
  float* bvm_f = (float*)alloc(DIM * 4);
  float* bc_f  = (float*)alloc(DIM * 4);
  unsigned short* Wtv_b = (unsigned short*)alloc(DIM * DIM * 2);
  unsigned short* Wvm_b = (unsigned short*)alloc(2 * DIM * DIM * 2);
  unsigned short* Wc_b  = (unsigned short*)alloc(2 * DIM * DIM * 2);
  unsigned short* Ym_b  = (unsigned short*)alloc((long)NEDGE * DIM * 2);  // 12.8 MB
  int* off_v  = (int*)alloc((NVERT + 1) * 4);
  int* cnt_e  = (int*)alloc(NEDGE * 4);
  int* cnt_v  = (int*)alloc(NVERT * 4);
  int* bsum_v = (int*)alloc(((NVERT + 1023) / 1024) * 4);
  int* adj_v  = (int*)alloc((long)NNZ_N * 4);   // 6.4 MB

  // ---- prep: weights + counter zeroing (one launch) ----
  prep_all<<<321 + (NEDGE + NVERT + 255) / 256, 256, 0, stream>>>(
      (const unsigned short*)X, b_tv, b_vm, W_tv, W_vm, W_te, W_em, b_te, b_em,
      btv_f, bvm_f, bc_f, Wtv_b, Wvm_b, Wc_b, flag, cnt_e, cnt_v);

  // ---- K1: e-count + adj_e scatter || gemm1 (Xp = X @ W_tv^T + b_tv) ----
  k_ecount_gemm1<<<2 * NB_QTR, 256, 0, stream>>>(
      (const int4*)v_idx, (const int4*)e_idx, cnt_e, adj_e,
      X, Wtv_b, btv_f, Xp_b, flag);

  // ---- K2: v-count tickets || fused(seg1 -> LDS -> gemm2 + LN) ----
  k_vcount_seg1gemm2<<<3 * ((NEDGE + 63) / 64), 256, 0, stream>>>(
      (const int4*)v_idx, cnt_v, tV4, cnt_e, adj_e, Xp_b,
      Y, Wc_b, bc_f, Ym_b, Yo, g_e, be_e, flag);

  // ---- v-side scan: cnt_v -> off_v partials + bsum (add folded into consumers) ----
  {
    int nbv = (NVERT + 1023) / 1024;
    scan_block<<<nbv, 1024, 0, stream>>>(cnt_v, off_v, bsum_v, NVERT);
    scan_sums<<<1, 1024, 0, stream>>>(bsum_v, nbv);
  }

  // ---- K3: write adj_v (scatter; zero atomics) ----
  k_wadjv<<<NB_QTR, 256, 0, stream>>>(
      (const int4*)v_idx, (const int4*)e_idx, tV4, off_v, bsum_v, adj_v);

  // ---- K4: fused(seg2 -> LDS -> gemm3 + LN) -> Xo ----
  k_seg2gemm3<<<(NVERT + 63) / 64, 256, 0, stream>>>(
      off_v, bsum_v, adj_v, Ym_b, X, Wvm_b, bvm_f, Xo, g_v, be_v, flag);
}

// Round 5
// 542.005 us; speedup vs baseline: 1.0714x; 1.0714x over previous
//
#include <hip/hip_runtime.h>
#include <stdint.h>

#define NVERT 100000
#define NEDGE 50000
#define DIM 128
#define NNZ_N 1600000
#define N4 (NNZ_N / 4)
#define CAP_E 96                 // fixed-capacity e-buckets; Poisson(32) tail @96 ~ 1e-18
#define NB_QTR 1563              // ceil(N4/256) = ceil(NVERT/64)
#define NB_G23 782               // ceil(50000/64)
#define MSG_STRIDE 256           // shorts per msg row slot (512B; bf16 row in first 256B)

typedef __attribute__((ext_vector_type(8))) short bf16x8;
typedef __attribute__((ext_vector_type(4))) float f32x4;

__device__ __forceinline__ unsigned short f32_to_bf16(float f) {
  union { float f; unsigned u; } v; v.f = f;
  unsigned r = v.u + 0x7fffu + ((v.u >> 16) & 1u);
  return (unsigned short)(r >> 16);
}
__device__ __forceinline__ float bf16_lo(unsigned u) {
  union { unsigned u; float f; } v; v.u = u << 16; return v.f;
}
__device__ __forceinline__ float bf16_hi(unsigned u) {
  union { unsigned u; float f; } v; v.u = u & 0xffff0000u; return v.f;
}
// dual-dtype load of external "float" inputs (f32 or bf16, runtime flag)
__device__ __forceinline__ float ldf(const void* p, long i, int bf) {
  if (bf) {
    union { unsigned u; float f; } v;
    v.u = (unsigned)((const unsigned short*)p)[i] << 16;
    return v.f;
  }
  return ((const float*)p)[i];
}
// 8-elem bf16 MFMA fragment from external (flag) array at element idx
__device__ __forceinline__ bf16x8 frag_ext(const void* A, long idx, int bf) {
  if (bf) return *(const bf16x8*)((const unsigned short*)A + idx);
  const float* f = (const float*)A + idx;
  float4 f0 = *(const float4*)f, f1 = *(const float4*)(f + 4);
  bf16x8 r;
  r[0] = (short)f32_to_bf16(f0.x); r[1] = (short)f32_to_bf16(f0.y);
  r[2] = (short)f32_to_bf16(f0.z); r[3] = (short)f32_to_bf16(f0.w);
  r[4] = (short)f32_to_bf16(f1.x); r[5] = (short)f32_to_bf16(f1.y);
  r[6] = (short)f32_to_bf16(f1.z); r[7] = (short)f32_to_bf16(f1.w);
  return r;
}

// per-block dtype detect (1024 samples of even-index u16 exponents)
__device__ __forceinline__ int block_flag(const unsigned short* x) {
  __shared__ int cnt;
  if (threadIdx.x == 0) cnt = 0;
  __syncthreads();
  int c = 0;
#pragma unroll
  for (int k = 0; k < 4; ++k) {
    unsigned short h = x[(threadIdx.x * 4 + k) * 2];
    int ex = (h >> 7) & 0xFF;
    c += (ex >= 100 && ex <= 140) ? 1 : 0;
  }
  atomicAdd(&cnt, c);
  __syncthreads();
  return cnt > 512;
}

// ---- prep0: flag + btv/bvm + W_tv + counter zeroing (652 blocks) ----
__global__ __launch_bounds__(256) void prep0(
    const unsigned short* __restrict__ Xu,
    const void* __restrict__ btv, const void* __restrict__ bvm,
    const void* __restrict__ Wtv,
    float* __restrict__ btvf, float* __restrict__ bvmf,
    unsigned short* __restrict__ Wtvb, int* __restrict__ flag,
    int* __restrict__ cnt_e, int* __restrict__ cnt_v) {
  int b = blockIdx.x, t = threadIdx.x;
  if (b >= 65) {                             // zero cnt_e (50000) + cnt_v (100000)
    int i = (b - 65) * 256 + t;
    if (i < NEDGE) cnt_e[i] = 0;
    else if (i < NEDGE + NVERT) cnt_v[i - NEDGE] = 0;
    return;
  }
  int bf = block_flag(Xu);
  if (b == 0) {
    if (t == 0) flag[0] = bf;
    if (t < 128) btvf[t] = ldf(btv, t, bf);
    else bvmf[t - 128] = ldf(bvm, t - 128, bf);
  } else {                                   // W_tv: 16384 elems over 64 blocks
    int i = (b - 1) * 256 + t;
    Wtvb[i] = f32_to_bf16(ldf(Wtv, i, bf));
  }
}

// ---- prep body folded into K1: Wvm (128 blocks) + Wc/bc (128 blocks) ----
__device__ __forceinline__ void prep_wc_body(
    int b, const void* __restrict__ Wvm, const void* __restrict__ Wte,
    const void* __restrict__ Wem, const void* __restrict__ bte,
    const void* __restrict__ bem, unsigned short* __restrict__ Wvmb,
    unsigned short* __restrict__ Wcb, float* __restrict__ bcf, int bf) {
  int t = threadIdx.x;
  if (b < 128) {                             // W_vm: 32768 elems
    int i = b * 256 + t;
    Wvmb[i] = f32_to_bf16(ldf(Wvm, i, bf));
  } else {                                   // fused Wc = Wte @ Wem, bc
    int n = b - 128, k = t;
    float acc = 0.f;
    for (int j = 0; j < 128; ++j)
      acc += ldf(Wte, n * 128 + j, bf) * ldf(Wem, j * 256 + k, bf);
    Wcb[n * 256 + k] = f32_to_bf16(acc);
    if (k == 0) {
      float bb = ldf(bte, n, bf);
      for (int j = 0; j < 128; ++j) bb += ldf(Wte, n * 128 + j, bf) * ldf(bem, j, bf);
      bcf[n] = bb;
    }
  }
}

// ---------- CSR build bodies ----------
// e-side: fixed-cap direct scatter (returning atomic IS the slot).
__device__ __forceinline__ void ecount_body(
    const int4* __restrict__ vi, const int4* __restrict__ ei,
    int* __restrict__ cnt_e, int* __restrict__ adj_e, int bid) {
  int i = bid * 256 + threadIdx.x;
  if (i >= N4) return;
  int4 e = ei[i], v = vi[i];
  int t;
  t = atomicAdd(&cnt_e[e.x], 1); if (t < CAP_E) adj_e[e.x * CAP_E + t] = v.x;
  t = atomicAdd(&cnt_e[e.y], 1); if (t < CAP_E) adj_e[e.y * CAP_E + t] = v.y;
  t = atomicAdd(&cnt_e[e.z], 1); if (t < CAP_E) adj_e[e.z * CAP_E + t] = v.z;
  t = atomicAdd(&cnt_e[e.w], 1); if (t < CAP_E) adj_e[e.w * CAP_E + t] = v.w;
}

// v-side: returning atomic -> ticket stored coalesced (exact CSR after scan).
__device__ __forceinline__ void vcount_body(
    const int4* __restrict__ vi, int* __restrict__ cnt_v,
    int4* __restrict__ tV, int bid) {
  int i = bid * 256 + threadIdx.x;
  if (i >= N4) return;
  int4 v = vi[i];
  int4 tv;
  tv.x = atomicAdd(&cnt_v[v.x], 1);
  tv.y = atomicAdd(&cnt_v[v.y], 1);
  tv.z = atomicAdd(&cnt_v[v.z], 1);
  tv.w = atomicAdd(&cnt_v[v.w], 1);
  tV[i] = tv;
}

// final position = partial_off + bsum + ticket (scan_add folded in here)
__device__ __forceinline__ void wadjv_body(
    const int4* __restrict__ vi, const int4* __restrict__ ei,
    const int4* __restrict__ tV, const int* __restrict__ off_v,
    const int* __restrict__ bsum, int* __restrict__ adj_v, int bid) {
  int i = bid * 256 + threadIdx.x;
  if (i >= N4) return;
  int4 e = ei[i], v = vi[i], tv = tV[i];
  adj_v[off_v[v.x] + bsum[v.x >> 10] + tv.x] = e.x;
  adj_v[off_v[v.y] + bsum[v.y >> 10] + tv.y] = e.y;
  adj_v[off_v[v.z] + bsum[v.z >> 10] + tv.z] = e.z;
  adj_v[off_v[v.w] + bsum[v.w >> 10] + tv.w] = e.w;
}

// ---------- scans (v-side only; add folded into consumers) ----------
__global__ __launch_bounds__(1024) void scan_block(const int* __restrict__ in,
                                                   int* __restrict__ out,
                                                   int* __restrict__ bsum, int n) {
  __shared__ int sd[1024];
  const int tid = threadIdx.x;
  const int i = blockIdx.x * 1024 + tid;
  int x = (i < n) ? in[i] : 0;
  sd[tid] = x;
  __syncthreads();
  int v = x;
  for (int s = 1; s < 1024; s <<= 1) {
    int t = (tid >= s) ? sd[tid - s] : 0;
    __syncthreads();
    v += t;
    sd[tid] = v;
    __syncthreads();
  }
  if (i < n) out[i] = v - x;
  if (tid == 1023) bsum[blockIdx.x] = v;
}

__global__ __launch_bounds__(1024) void scan_sums(int* __restrict__ bsum, int nb) {
  __shared__ int sd[1024];
  const int tid = threadIdx.x;
  int x = (tid < nb) ? bsum[tid] : 0;
  sd[tid] = x;
  __syncthreads();
  int v = x;
  for (int s = 1; s < 1024; s <<= 1) {
    int t = (tid >= s) ? sd[tid - s] : 0;
    __syncthreads();
    v += t;
    sd[tid] = v;
    __syncthreads();
  }
  if (tid < nb) bsum[tid] = v - x;
}

// ---------- segment mean body: 4 segs/wave, 16 lanes x 8 cols, x8-unrolled ----------
// Output: bf16 row in first 256B of a 512B slot (row-aligned with f32 in-place overwrite).
// CAPMODE: segments at fixed stride CAP_E, length cnt[seg].
// else: CSR offsets = off[seg] + bsum[seg>>10], tail = total.
template<bool CAPMODE>
__device__ __forceinline__ void seg_body(
    const int* __restrict__ off_or_cnt, const int* __restrict__ adj,
    const unsigned short* __restrict__ tbl, unsigned short* __restrict__ out,
    int nseg, int nrows, const int* __restrict__ bsum, int total, int bid) {
  const int seg = (bid * 256 + threadIdx.x) >> 4;
  const int l = threadIdx.x & 15;
  if (seg >= nseg) return;
  int s, e, cnt;
  if (CAPMODE) {
    cnt = off_or_cnt[seg];
    s = seg * CAP_E;
    e = s + (cnt < CAP_E ? cnt : CAP_E);
  } else {
    s = off_or_cnt[seg] + bsum[seg >> 10];
    e = (seg + 1 < nseg) ? off_or_cnt[seg + 1] + bsum[(seg + 1) >> 10] : total;
    cnt = e - s;
  }
  float a0 = 0, a1 = 0, a2 = 0, a3 = 0, a4 = 0, a5 = 0, a6 = 0, a7 = 0;
#define ROW(r, u)                                      \
  if ((unsigned)r >= (unsigned)nrows) r = 0;           \
  uint4 u = *(const uint4*)(tbl + (long)r * DIM + l * 8);
#define ACC(u)                                         \
  a0 += bf16_lo(u.x); a1 += bf16_hi(u.x);              \
  a2 += bf16_lo(u.y); a3 += bf16_hi(u.y);              \
  a4 += bf16_lo(u.z); a5 += bf16_hi(u.z);              \
  a6 += bf16_lo(u.w); a7 += bf16_hi(u.w);
  int i = s;
  for (; i + 8 <= e; i += 8) {
    int r0 = adj[i],     r1 = adj[i + 1], r2 = adj[i + 2], r3 = adj[i + 3];
    int r4 = adj[i + 4], r5 = adj[i + 5], r6 = adj[i + 6], r7 = adj[i + 7];
    ROW(r0, u0) ROW(r1, u1) ROW(r2, u2) ROW(r3, u3)
    ROW(r4, u4) ROW(r5, u5) ROW(r6, u6) ROW(r7, u7)
    ACC(u0) ACC(u1) ACC(u2) ACC(u3) ACC(u4) ACC(u5) ACC(u6) ACC(u7)
  }
  for (; i + 4 <= e; i += 4) {
    int r0 = adj[i], r1 = adj[i + 1], r2 = adj[i + 2], r3 = adj[i + 3];
    ROW(r0, u0) ROW(r1, u1) ROW(r2, u2) ROW(r3, u3)
    ACC(u0) ACC(u1) ACC(u2) ACC(u3)
  }
  for (; i < e; ++i) {
    int r = adj[i];
    ROW(r, u)
    ACC(u)
  }
#undef ACC
#undef ROW
  float inv = (cnt > 0) ? 1.f / (float)cnt : 0.f;
  bf16x8 r;
  r[0] = (short)f32_to_bf16(a0 * inv); r[1] = (short)f32_to_bf16(a1 * inv);
  r[2] = (short)f32_to_bf16(a2 * inv); r[3] = (short)f32_to_bf16(a3 * inv);
  r[4] = (short)f32_to_bf16(a4 * inv); r[5] = (short)f32_to_bf16(a5 * inv);
  r[6] = (short)f32_to_bf16(a6 * inv); r[7] = (short)f32_to_bf16(a7 * inv);
  *(bf16x8*)(out + (long)seg * MSG_STRIDE + l * 8) = r;
}

// ---------- MFMA GEMM bodies ----------
// plain K=128: out(bf16)[M][128] = A[M][128] @ B^T + bias
__device__ __forceinline__ void gemm1_body(
    int bid, const void* __restrict__ A0,
    const unsigned short* __restrict__ Bw, const float* __restrict__ biasf,
    unsigned short* __restrict__ outb, int M, int bf) {
  const int wave = threadIdx.x >> 6;
  const int lane = threadIdx.x & 63;
  const int m0 = bid * 64 + wave * 16;
  if (m0 >= M) return;
  const int c = lane & 15;
  const int q = lane >> 4;
  const long arow = m0 + c;
  f32x4 acc[8];
#pragma unroll
  for (int t = 0; t < 8; ++t) acc[t] = (f32x4){0.f, 0.f, 0.f, 0.f};
#pragma unroll
  for (int ks = 0; ks < 4; ++ks) {
    const int kk = ks * 32 + q * 8;
    bf16x8 a = frag_ext(A0, arow * 128 + kk, bf);
#pragma unroll
    for (int t = 0; t < 8; ++t) {
      bf16x8 b = *(const bf16x8*)(Bw + (long)(t * 16 + c) * 128 + kk);
      acc[t] = __builtin_amdgcn_mfma_f32_16x16x32_bf16(a, b, acc[t], 0, 0, 0);
    }
  }
  // C/D layout [m89-verified]: col = t*16 + c, row = m0 + q*4 + reg
#pragma unroll
  for (int t = 0; t < 8; ++t) {
    float bv = biasf[t * 16 + c];
    int col = t * 16 + c;
#pragma unroll
    for (int i = 0; i < 4; ++i)
      outb[(long)(m0 + q * 4 + i) * DIM + col] = f32_to_bf16(acc[t][i] + bv);
  }
}

// K=256 split: k<128 from external A0 (flag dtype), k>=128 from strided-bf16 msg.
// LN+relu epilogue -> outf (in-place safe: same-row aliasing, rows per wave).
template<bool STORE_BF16>
__device__ __forceinline__ void gemm23_body(
    int bid, int rowbase, int M,
    const void* __restrict__ A0, const unsigned short* __restrict__ A1b,
    const unsigned short* __restrict__ Bw, const float* __restrict__ biasf,
    unsigned short* __restrict__ outb, float* __restrict__ outf,
    const void* __restrict__ gw_, const void* __restrict__ bw_, int bf) {
  const int wave = threadIdx.x >> 6;
  const int lane = threadIdx.x & 63;
  const int m0 = rowbase + bid * 64 + wave * 16;
  if (m0 >= M) return;
  const int c = lane & 15;
  const int q = lane >> 4;
  const long arow = m0 + c;

  f32x4 acc[8];
#pragma unroll
  for (int t = 0; t < 8; ++t) acc[t] = (f32x4){0.f, 0.f, 0.f, 0.f};
#pragma unroll
  for (int ks = 0; ks < 8; ++ks) {
    const int kk = ks * 32 + q * 8;
    bf16x8 a;
    if (ks >= 4) a = *(const bf16x8*)(A1b + arow * MSG_STRIDE + (kk - 128));
    else         a = frag_ext(A0, arow * 128 + kk, bf);
#pragma unroll
    for (int t = 0; t < 8; ++t) {
      bf16x8 b = *(const bf16x8*)(Bw + (long)(t * 16 + c) * 256 + kk);
      acc[t] = __builtin_amdgcn_mfma_f32_16x16x32_bf16(a, b, acc[t], 0, 0, 0);
    }
  }
#pragma unroll
  for (int t = 0; t < 8; ++t) {
    float bv = biasf[t * 16 + c];
#pragma unroll
    for (int i = 0; i < 4; ++i) acc[t][i] += bv;
  }
  if (STORE_BF16) {
#pragma unroll
    for (int t = 0; t < 8; ++t) {
      int col = t * 16 + c;
#pragma unroll
      for (int i = 0; i < 4; ++i)
        outb[(long)(m0 + q * 4 + i) * DIM + col] = f32_to_bf16(acc[t][i]);
    }
  }
  float sum[4] = {0, 0, 0, 0}, sq[4] = {0, 0, 0, 0};
#pragma unroll
  for (int t = 0; t < 8; ++t)
#pragma unroll
    for (int i = 0; i < 4; ++i) { float v = acc[t][i]; sum[i] += v; sq[i] += v * v; }
#pragma unroll
  for (int m = 1; m <= 8; m <<= 1) {
#pragma unroll
    for (int i = 0; i < 4; ++i) {
      sum[i] += __shfl_xor(sum[i], m, 64);
      sq[i]  += __shfl_xor(sq[i], m, 64);
    }
  }
  float mean[4], rstd[4];
#pragma unroll
  for (int i = 0; i < 4; ++i) {
    mean[i] = sum[i] * (1.0f / 128.0f);
    float var = sq[i] * (1.0f / 128.0f) - mean[i] * mean[i];
    rstd[i] = rsqrtf(var + 1e-5f);
  }
#pragma unroll
  for (int t = 0; t < 8; ++t) {
    int col = t * 16 + c;
    float gv = ldf(gw_, col, bf), bv = ldf(bw_, col, bf);
#pragma unroll
    for (int i = 0; i < 4; ++i) {
      float v = (acc[t][i] - mean[i]) * rstd[i] * gv + bv;
      v = v > 0.f ? v : 0.f;
      outf[(long)(m0 + q * 4 + i) * DIM + col] = v;
    }
  }
}

// ---------- fused heterogeneous launches ----------
// K1: b<256 -> Wvm/Wc prep ; then even -> e-count scatter ; odd -> gemm1
__global__ __launch_bounds__(256) void k1_prep_ecount_gemm1(
    const int4* __restrict__ vi, const int4* __restrict__ ei,
    int* __restrict__ cnt_e, int* __restrict__ adj_e,
    const void* __restrict__ X, const unsigned short* __restrict__ Wtvb,
    const float* __restrict__ btvf, unsigned short* __restrict__ Xp_b,
    const void* __restrict__ Wvm, const void* __restrict__ Wte,
    const void* __restrict__ Wem, const void* __restrict__ bte,
    const void* __restrict__ bem, unsigned short* __restrict__ Wvmb,
    unsigned short* __restrict__ Wcb, float* __restrict__ bcf,
    const int* __restrict__ flagp) {
  int b = blockIdx.x;
  if (b < 256) {
    prep_wc_body(b, Wvm, Wte, Wem, bte, bem, Wvmb, Wcb, bcf, *flagp);
    return;
  }
  int b2 = b - 256;
  if (b2 & 1)
    gemm1_body(b2 >> 1, X, Wtvb, btvf, Xp_b, NVERT, *flagp);
  else
    ecount_body(vi, ei, cnt_e, adj_e, b2 >> 1);
}

// K2: %3==0 -> v-count tickets (atomic-bound) ; else -> seg1 (gather-bound)
__global__ __launch_bounds__(256) void k2_vcount_seg1(
    const int4* __restrict__ vi, int* __restrict__ cnt_v, int4* __restrict__ tV,
    const int* __restrict__ cnt_e, const int* __restrict__ adj_e,
    const unsigned short* __restrict__ Xp_b, unsigned short* __restrict__ msg_e) {
  int r = blockIdx.x % 3, q = blockIdx.x / 3;
  if (r == 0)
    vcount_body(vi, cnt_v, tV, q);
  else
    seg_body<true>(cnt_e, adj_e, Xp_b, msg_e, NEDGE, NVERT, nullptr, 0,
                   q * 2 + (r - 1));
}

// K3: %3==2 -> gemm2 (compute-bound) ; else -> write_adj_v (scatter-bound)
__global__ __launch_bounds__(256) void k3_wadjv_gemm2(
    const int4* __restrict__ vi, const int4* __restrict__ ei,
    const int4* __restrict__ tV, const int* __restrict__ off_v,
    const int* __restrict__ bsum, int* __restrict__ adj_v,
    const void* __restrict__ Y, const unsigned short* __restrict__ msg_e,
    const unsigned short* __restrict__ Wcb, const float* __restrict__ bcf,
    unsigned short* __restrict__ Ym_b, float* __restrict__ Yo,
    const void* __restrict__ g_e, const void* __restrict__ be_e,
    const int* __restrict__ flagp) {
  int r = blockIdx.x % 3, q = blockIdx.x / 3;
  if (r == 2)
    gemm23_body<true>(q, 0, NEDGE, Y, msg_e, Wcb, bcf, Ym_b, Yo, g_e, be_e,
                      *flagp);
  else
    wadjv_body(vi, ei, tV, off_v, bsum, adj_v, q * 2 + r);
}

// K4a: seg2 half0 (vertex segs [0, 50000))
__global__ __launch_bounds__(256) void k4a_seg2(
    const int* __restrict__ off_v, const int* __restrict__ bsum,
    const int* __restrict__ adj_v, const unsigned short* __restrict__ Ym_b,
    unsigned short* __restrict__ msg_v) {
  seg_body<false>(off_v, adj_v, Ym_b, msg_v, NVERT, NEDGE, bsum, NNZ_N,
                  blockIdx.x);
}

// K4b: %5==4 -> gemm3 half0 (rows [0,50000)) ; else -> seg2 half1 ([50000,100000))
__global__ __launch_bounds__(256) void k4b_seg2_gemm3(
    const int* __restrict__ off_v, const int* __restrict__ bsum,
    const int* __restrict__ adj_v, const unsigned short* __restrict__ Ym_b,
    unsigned short* __restrict__ msg_v,
    const void* __restrict__ X, const unsigned short* __restrict__ Wvmb,
    const float* __restrict__ bvmf, float* __restrict__ Xo,
    const void* __restrict__ g_v, const void* __restrict__ be_v,
    const int* __restrict__ flagp) {
  int r = blockIdx.x % 5, q = blockIdx.x / 5;
  if (r == 4)
    gemm23_body<false>(q, 0, NVERT / 2, X, msg_v, Wvmb, bvmf, nullptr, Xo,
                       g_v, be_v, *flagp);
  else
    seg_body<false>(off_v, adj_v, Ym_b, msg_v, NVERT, NEDGE, bsum, NNZ_N,
                    3125 + q * 4 + r);
}

// K5: gemm3 half1 (rows [50000,100000))
__global__ __launch_bounds__(256) void k5_gemm3(
    const void* __restrict__ X, const unsigned short* __restrict__ msg_v,
    const unsigned short* __restrict__ Wvmb, const float* __restrict__ bvmf,
    float* __restrict__ Xo, const void* __restrict__ g_v,
    const void* __restrict__ be_v, const int* __restrict__ flagp) {
  gemm23_body<false>(blockIdx.x, NVERT / 2, NVERT, X, msg_v, Wvmb, bvmf,
                     nullptr, Xo, g_v, be_v, *flagp);
}

extern "C" void kernel_launch(void* const* d_in, const int* in_sizes, int n_in,
                              void* d_out, int out_size, void* d_ws, size_t ws_size,
                              hipStream_t stream) {
  const void* X    = d_in[0];
  const void* Y    = d_in[1];
  const int*  v_idx = (const int*)d_in[2];
  const int*  e_idx = (const int*)d_in[3];
  const void* W_tv = d_in[4];
  const void* b_tv = d_in[5];
  const void* W_te = d_in[6];
  const void* b_te = d_in[7];
  const void* W_em = d_in[8];
  const void* b_em = d_in[9];
  const void* W_vm = d_in[10];
  const void* b_vm = d_in[11];
  const void* g_v  = d_in[12];
  const void* be_v = d_in[13];
  const void* g_e  = d_in[14];
  const void* be_e = d_in[15];

  // d_out (76.8 MB) liveness packing (msg rows = bf16 in first 256B of 512B slots,
  // row-aligned with the f32 outputs that overwrite them in place):
  //  K1:  Xp_b(bf16) [0,25.6M) ; adj_e [25.6,44.8M)
  //  K2:  tV [44.8,51.2M) ; msg_e(strided bf16) [51.2,76.8M)
  //  K3:  Yo(f32) [51.2,76.8M) in-place over msg_e (same-row aliasing only)
  //  K4a: msg_v rows [0,50k) -> bytes [0,25.6M) over dead Xp
  //  K4b: seg half1 -> bytes [25.6,51.2M) over dead adj_e/tV ; gemm3 half0 writes
  //       Xo rows [0,50k) = bytes [0,25.6M) in-place over its own msg rows
  //  K5:  Xo rows [50k,100k) = bytes [25.6,51.2M) in-place
  unsigned short* Xp_b  = (unsigned short*)d_out;
  int*   adj_e = (int*)((char*)d_out + 25600000);   // 50000*96*4 = 19.2 MB
  int4*  tV4   = (int4*)((char*)d_out + 44800000);  // 1.6M ints = 6.4 MB
  unsigned short* msg_e = (unsigned short*)((char*)d_out + 51200000);
  float* Yo    = (float*)((char*)d_out + 51200000);
  unsigned short* msg_v = (unsigned short*)d_out;
  float* Xo    = (float*)d_out;

  // ws ~20.5 MB
  char* p = (char*)d_ws;
  auto alloc = [&](size_t n) { char* r = p; p += (n + 255) & ~(size_t)255; return r; };
  int*   flag  = (int*)alloc(4);
  float* btv_f = (float*)alloc(DIM * 4);
  float* bvm_f = (float*)alloc(DIM * 4);
  float* bc_f  = (float*)alloc(DIM * 4);
  unsigned short* Wtv_b = (unsigned short*)alloc(DIM * DIM * 2);
  unsigned short* Wvm_b = (unsigned short*)alloc(2 * DIM * DIM * 2);
  unsigned short* Wc_b  = (unsigned short*)alloc(2 * DIM * DIM * 2);
  unsigned short* Ym_b  = (unsigned short*)alloc((long)NEDGE * DIM * 2);  // 12.8 MB
  int* off_v  = (int*)alloc((NVERT + 1) * 4);
  int* cnt_e  = (int*)alloc(NEDGE * 4);
  int* cnt_v  = (int*)alloc(NVERT * 4);
  int* bsum_v = (int*)alloc(((NVERT + 1023) / 1024) * 4);
  int* adj_v  = (int*)alloc((long)NNZ_N * 4);   // 6.4 MB

  // ---- prep0: flag + btv/bvm + W_tv + zero counters ----
  prep0<<<65 + (NEDGE + NVERT + 255) / 256, 256, 0, stream>>>(
      (const unsigned short*)X, b_tv, b_vm, W_tv, btv_f, bvm_f, Wtv_b, flag,
      cnt_e, cnt_v);

  // ---- K1: Wvm/Wc prep || e-count+adj_e scatter || gemm1 ----
  k1_prep_ecount_gemm1<<<256 + 2 * NB_QTR, 256, 0, stream>>>(
      (const int4*)v_idx, (const int4*)e_idx, cnt_e, adj_e,
      X, Wtv_b, btv_f, Xp_b,
      W_vm, W_te, W_em, b_te, b_em, Wvm_b, Wc_b, bc_f, flag);

  // ---- K2: v-count tickets || seg1 (msg_e = seg_mean(Xp[v] by e), bf16) ----
  k2_vcount_seg1<<<3 * NB_QTR, 256, 0, stream>>>(
      (const int4*)v_idx, cnt_v, tV4, cnt_e, adj_e, Xp_b, msg_e);

  // ---- v-side scan: cnt_v -> off_v partials + bsum (add folded into consumers) ----
  {
    int nbv = (NVERT + 1023) / 1024;
    scan_block<<<nbv, 1024, 0, stream>>>(cnt_v, off_v, bsum_v, NVERT);
    scan_sums<<<1, 1024, 0, stream>>>(bsum_v, nbv);
  }

  // ---- K3: write_adj_v || gemm2 (Ym/Yo) ----
  k3_wadjv_gemm2<<<3 * NB_G23, 256, 0, stream>>>(
      (const int4*)v_idx, (const int4*)e_idx, tV4, off_v, bsum_v, adj_v,
      Y, msg_e, Wc_b, bc_f, Ym_b, Yo, g_e, be_e, flag);

  // ---- K4a: seg2 half0 ----
  k4a_seg2<<<3125, 256, 0, stream>>>(off_v, bsum_v, adj_v, Ym_b, msg_v);

  // ---- K4b: seg2 half1 || gemm3 half0 ----
  k4b_seg2_gemm3<<<5 * NB_G23, 256, 0, stream>>>(
      off_v, bsum_v, adj_v, Ym_b, msg_v, X, Wvm_b, bvm_f, Xo, g_v, be_v, flag);

  // ---- K5: gemm3 half1 ----
  k5_gemm3<<<NB_G23, 256, 0, stream>>>(
      X, msg_v, Wvm_b, bvm_f, Xo, g_v, be_v, flag);
}

// Round 7
// 523.114 us; speedup vs baseline: 1.1100x; 1.0361x over previous
//
#include <hip/hip_runtime.h>
#include <stdint.h>

#define NVERT 100000
#define NEDGE 50000
#define DIM 128
#define NNZ_N 1600000
#define N4 (NNZ_N / 4)
#define CAP_E 96                 // e-buckets: mean 32, max ~58 -> 96 safe
#define CAP_V 56                 // v-buckets: mean 16, max ~36 -> 56 safe (ushort ids)
#define NB_QTR 1563              // ceil(N4/256) = ceil(NVERT/64)
#define NB_G23 782               // ceil(50000/64)
#define MSG_STRIDE 256           // shorts per msg row slot (512B; bf16 row in first 256B)

typedef __attribute__((ext_vector_type(8))) short bf16x8;
typedef __attribute__((ext_vector_type(4))) float f32x4;

__device__ __forceinline__ unsigned short f32_to_bf16(float f) {
  union { float f; unsigned u; } v; v.f = f;
  unsigned r = v.u + 0x7fffu + ((v.u >> 16) & 1u);
  return (unsigned short)(r >> 16);
}
__device__ __forceinline__ float bf16_lo(unsigned u) {
  union { unsigned u; float f; } v; v.u = u << 16; return v.f;
}
__device__ __forceinline__ float bf16_hi(unsigned u) {
  union { unsigned u; float f; } v; v.u = u & 0xffff0000u; return v.f;
}
// dual-dtype load of external "float" inputs (f32 or bf16, runtime flag)
__device__ __forceinline__ float ldf(const void* p, long i, int bf) {
  if (bf) {
    union { unsigned u; float f; } v;
    v.u = (unsigned)((const unsigned short*)p)[i] << 16;
    return v.f;
  }
  return ((const float*)p)[i];
}
// 8-elem bf16 MFMA fragment from external (flag) array at element idx
__device__ __forceinline__ bf16x8 frag_ext(const void* A, long idx, int bf) {
  if (bf) return *(const bf16x8*)((const unsigned short*)A + idx);
  const float* f = (const float*)A + idx;
  float4 f0 = *(const float4*)f, f1 = *(const float4*)(f + 4);
  bf16x8 r;
  r[0] = (short)f32_to_bf16(f0.x); r[1] = (short)f32_to_bf16(f0.y);
  r[2] = (short)f32_to_bf16(f0.z); r[3] = (short)f32_to_bf16(f0.w);
  r[4] = (short)f32_to_bf16(f1.x); r[5] = (short)f32_to_bf16(f1.y);
  r[6] = (short)f32_to_bf16(f1.z); r[7] = (short)f32_to_bf16(f1.w);
  return r;
}

// per-block dtype detect (1024 samples of even-index u16 exponents)
__device__ __forceinline__ int block_flag(const unsigned short* x) {
  __shared__ int cnt;
  if (threadIdx.x == 0) cnt = 0;
  __syncthreads();
  int c = 0;
#pragma unroll
  for (int k = 0; k < 4; ++k) {
    unsigned short h = x[(threadIdx.x * 4 + k) * 2];
    int ex = (h >> 7) & 0xFF;
    c += (ex >= 100 && ex <= 140) ? 1 : 0;
  }
  atomicAdd(&cnt, c);
  __syncthreads();
  return cnt > 512;
}

// ---- prep0: flag + btv/bvm + W_tv + counter zeroing (652 blocks) ----
__global__ __launch_bounds__(256) void prep0(
    const unsigned short* __restrict__ Xu,
    const void* __restrict__ btv, const void* __restrict__ bvm,
    const void* __restrict__ Wtv,
    float* __restrict__ btvf, float* __restrict__ bvmf,
    unsigned short* __restrict__ Wtvb, int* __restrict__ flag,
    int* __restrict__ cnt_e, int* __restrict__ cnt_v) {
  int b = blockIdx.x, t = threadIdx.x;
  if (b >= 65) {                             // zero cnt_e (50000) + cnt_v (100000)
    int i = (b - 65) * 256 + t;
    if (i < NEDGE) cnt_e[i] = 0;
    else if (i < NEDGE + NVERT) cnt_v[i - NEDGE] = 0;
    return;
  }
  int bf = block_flag(Xu);
  if (b == 0) {
    if (t == 0) flag[0] = bf;
    if (t < 128) btvf[t] = ldf(btv, t, bf);
    else bvmf[t - 128] = ldf(bvm, t - 128, bf);
  } else {                                   // W_tv: 16384 elems over 64 blocks
    int i = (b - 1) * 256 + t;
    Wtvb[i] = f32_to_bf16(ldf(Wtv, i, bf));
  }
}

// ---- prep body folded into K1: Wvm (128 blocks) + Wc/bc (128 blocks) ----
__device__ __forceinline__ void prep_wc_body(
    int b, const void* __restrict__ Wvm, const void* __restrict__ Wte,
    const void* __restrict__ Wem, const void* __restrict__ bte,
    const void* __restrict__ bem, unsigned short* __restrict__ Wvmb,
    unsigned short* __restrict__ Wcb, float* __restrict__ bcf, int bf) {
  int t = threadIdx.x;
  if (b < 128) {                             // W_vm: 32768 elems
    int i = b * 256 + t;
    Wvmb[i] = f32_to_bf16(ldf(Wvm, i, bf));
  } else {                                   // fused Wc = Wte @ Wem, bc
    int n = b - 128, k = t;
    float acc = 0.f;
    for (int j = 0; j < 128; ++j)
      acc += ldf(Wte, n * 128 + j, bf) * ldf(Wem, j * 256 + k, bf);
    Wcb[n * 256 + k] = f32_to_bf16(acc);
    if (k == 0) {
      float bb = ldf(bte, n, bf);
      for (int j = 0; j < 128; ++j) bb += ldf(Wte, n * 128 + j, bf) * ldf(bem, j, bf);
      bcf[n] = bb;
    }
  }
}

// ---------- CSR build bodies: fixed-cap direct scatter, both sides ----------
// returning atomic IS the slot; ticket order == prior exact-CSR order (bit-identical).
__device__ __forceinline__ void ecount_body(
    const int4* __restrict__ vi, const int4* __restrict__ ei,
    int* __restrict__ cnt_e, int* __restrict__ adj_e, int bid) {
  int i = bid * 256 + threadIdx.x;
  if (i >= N4) return;
  int4 e = ei[i], v = vi[i];
  int t;
  t = atomicAdd(&cnt_e[e.x], 1); if (t < CAP_E) adj_e[e.x * CAP_E + t] = v.x;
  t = atomicAdd(&cnt_e[e.y], 1); if (t < CAP_E) adj_e[e.y * CAP_E + t] = v.y;
  t = atomicAdd(&cnt_e[e.z], 1); if (t < CAP_E) adj_e[e.z * CAP_E + t] = v.z;
  t = atomicAdd(&cnt_e[e.w], 1); if (t < CAP_E) adj_e[e.w * CAP_E + t] = v.w;
}

// v-side: edge ids < 50000 fit ushort -> 11.2 MB cap table, no tickets/scan/wadjv.
__device__ __forceinline__ void vcount_body(
    const int4* __restrict__ vi, const int4* __restrict__ ei,
    int* __restrict__ cnt_v, unsigned short* __restrict__ adj_v, int bid) {
  int i = bid * 256 + threadIdx.x;
  if (i >= N4) return;
  int4 v = vi[i], e = ei[i];
  int t;
  t = atomicAdd(&cnt_v[v.x], 1); if (t < CAP_V) adj_v[v.x * CAP_V + t] = (unsigned short)e.x;
  t = atomicAdd(&cnt_v[v.y], 1); if (t < CAP_V) adj_v[v.y * CAP_V + t] = (unsigned short)e.y;
  t = atomicAdd(&cnt_v[v.z], 1); if (t < CAP_V) adj_v[v.z * CAP_V + t] = (unsigned short)e.z;
  t = atomicAdd(&cnt_v[v.w], 1); if (t < CAP_V) adj_v[v.w * CAP_V + t] = (unsigned short)e.w;
}

// ---------- segment mean: 4 segs/wave, 16 lanes x 8 cols, x8-unrolled, cap-mode ----------
// Output: bf16 row in first 256B of a 512B slot (row-aligned with f32 in-place overwrite).
template<typename IT, int CAP>
__device__ __forceinline__ void seg_body(
    const int* __restrict__ cntp, const IT* __restrict__ adj,
    const unsigned short* __restrict__ tbl, unsigned short* __restrict__ out,
    int nseg, int nrows, int bid) {
  const int seg = (bid * 256 + threadIdx.x) >> 4;
  const int l = threadIdx.x & 15;
  if (seg >= nseg) return;
  int cnt = cntp[seg];
  int s = seg * CAP;
  int e = s + (cnt < CAP ? cnt : CAP);
  float a0 = 0, a1 = 0, a2 = 0, a3 = 0, a4 = 0, a5 = 0, a6 = 0, a7 = 0;
#define ROW(r, u)                                      \
  if ((unsigned)r >= (unsigned)nrows) r = 0;           \
  uint4 u = *(const uint4*)(tbl + (long)r * DIM + l * 8);
#define ACC(u)                                         \
  a0 += bf16_lo(u.x); a1 += bf16_hi(u.x);              \
  a2 += bf16_lo(u.y); a3 += bf16_hi(u.y);              \
  a4 += bf16_lo(u.z); a5 += bf16_hi(u.z);              \
  a6 += bf16_lo(u.w); a7 += bf16_hi(u.w);
  int i = s;
  for (; i + 8 <= e; i += 8) {
    int r0 = adj[i],     r1 = adj[i + 1], r2 = adj[i + 2], r3 = adj[i + 3];
    int r4 = adj[i + 4], r5 = adj[i + 5], r6 = adj[i + 6], r7 = adj[i + 7];
    ROW(r0, u0) ROW(r1, u1) ROW(r2, u2) ROW(r3, u3)
    ROW(r4, u4) ROW(r5, u5) ROW(r6, u6) ROW(r7, u7)
    ACC(u0) ACC(u1) ACC(u2) ACC(u3) ACC(u4) ACC(u5) ACC(u6) ACC(u7)
  }
  for (; i + 4 <= e; i += 4) {
    int r0 = adj[i], r1 = adj[i + 1], r2 = adj[i + 2], r3 = adj[i + 3];
    ROW(r0, u0) ROW(r1, u1) ROW(r2, u2) ROW(r3, u3)
    ACC(u0) ACC(u1) ACC(u2) ACC(u3)
  }
  for (; i < e; ++i) {
    int r = adj[i];
    ROW(r, u)
    ACC(u)
  }
#undef ACC
#undef ROW
  float inv = (cnt > 0) ? 1.f / (float)cnt : 0.f;
  bf16x8 r;
  r[0] = (short)f32_to_bf16(a0 * inv); r[1] = (short)f32_to_bf16(a1 * inv);
  r[2] = (short)f32_to_bf16(a2 * inv); r[3] = (short)f32_to_bf16(a3 * inv);
  r[4] = (short)f32_to_bf16(a4 * inv); r[5] = (short)f32_to_bf16(a5 * inv);
  r[6] = (short)f32_to_bf16(a6 * inv); r[7] = (short)f32_to_bf16(a7 * inv);
  *(bf16x8*)(out + (long)seg * MSG_STRIDE + l * 8) = r;
}

// ---------- MFMA GEMM bodies ----------
// plain K=128: out(bf16)[M][128] = A[M][128] @ B^T + bias
__device__ __forceinline__ void gemm1_body(
    int bid, const void* __restrict__ A0,
    const unsigned short* __restrict__ Bw, const float* __restrict__ biasf,
    unsigned short* __restrict__ outb, int M, int bf) {
  const int wave = threadIdx.x >> 6;
  const int lane = threadIdx.x & 63;
  const int m0 = bid * 64 + wave * 16;
  if (m0 >= M) return;
  const int c = lane & 15;
  const int q = lane >> 4;
  const long arow = m0 + c;
  f32x4 acc[8];
#pragma unroll
  for (int t = 0; t < 8; ++t) acc[t] = (f32x4){0.f, 0.f, 0.f, 0.f};
#pragma unroll
  for (int ks = 0; ks < 4; ++ks) {
    const int kk = ks * 32 + q * 8;
    bf16x8 a = frag_ext(A0, arow * 128 + kk, bf);
#pragma unroll
    for (int t = 0; t < 8; ++t) {
      bf16x8 b = *(const bf16x8*)(Bw + (long)(t * 16 + c) * 128 + kk);
      acc[t] = __builtin_amdgcn_mfma_f32_16x16x32_bf16(a, b, acc[t], 0, 0, 0);
    }
  }
  // C/D layout [m89-verified]: col = t*16 + c, row = m0 + q*4 + reg
#pragma unroll
  for (int t = 0; t < 8; ++t) {
    float bv = biasf[t * 16 + c];
    int col = t * 16 + c;
#pragma unroll
    for (int i = 0; i < 4; ++i)
      outb[(long)(m0 + q * 4 + i) * DIM + col] = f32_to_bf16(acc[t][i] + bv);
  }
}

// K=256 split: k<128 from external A0 (flag dtype), k>=128 from strided-bf16 msg.
// LN+relu epilogue -> outf (in-place safe: same-row aliasing, rows per wave).
template<bool STORE_BF16>
__device__ __forceinline__ void gemm23_body(
    int bid, int rowbase, int M,
    const void* __restrict__ A0, const unsigned short* __restrict__ A1b,
    const unsigned short* __restrict__ Bw, const float* __restrict__ biasf,
    unsigned short* __restrict__ outb, float* __restrict__ outf,
    const void* __restrict__ gw_, const void* __restrict__ bw_, int bf) {
  const int wave = threadIdx.x >> 6;
  const int lane = threadIdx.x & 63;
  const int m0 = rowbase + bid * 64 + wave * 16;
  if (m0 >= M) return;
  const int c = lane & 15;
  const int q = lane >> 4;
  const long arow = m0 + c;

  f32x4 acc[8];
#pragma unroll
  for (int t = 0; t < 8; ++t) acc[t] = (f32x4){0.f, 0.f, 0.f, 0.f};
#pragma unroll
  for (int ks = 0; ks < 8; ++ks) {
    const int kk = ks * 32 + q * 8;
    bf16x8 a;
    if (ks >= 4) a = *(const bf16x8*)(A1b + arow * MSG_STRIDE + (kk - 128));
    else         a = frag_ext(A0, arow * 128 + kk, bf);
#pragma unroll
    for (int t = 0; t < 8; ++t) {
      bf16x8 b = *(const bf16x8*)(Bw + (long)(t * 16 + c) * 256 + kk);
      acc[t] = __builtin_amdgcn_mfma_f32_16x16x32_bf16(a, b, acc[t], 0, 0, 0);
    }
  }
#pragma unroll
  for (int t = 0; t < 8; ++t) {
    float bv = biasf[t * 16 + c];
#pragma unroll
    for (int i = 0; i < 4; ++i) acc[t][i] += bv;
  }
  if (STORE_BF16) {
#pragma unroll
    for (int t = 0; t < 8; ++t) {
      int col = t * 16 + c;
#pragma unroll
      for (int i = 0; i < 4; ++i)
        outb[(long)(m0 + q * 4 + i) * DIM + col] = f32_to_bf16(acc[t][i]);
    }
  }
  float sum[4] = {0, 0, 0, 0}, sq[4] = {0, 0, 0, 0};
#pragma unroll
  for (int t = 0; t < 8; ++t)
#pragma unroll
    for (int i = 0; i < 4; ++i) { float v = acc[t][i]; sum[i] += v; sq[i] += v * v; }
#pragma unroll
  for (int m = 1; m <= 8; m <<= 1) {
#pragma unroll
    for (int i = 0; i < 4; ++i) {
      sum[i] += __shfl_xor(sum[i], m, 64);
      sq[i]  += __shfl_xor(sq[i], m, 64);
    }
  }
  float mean[4], rstd[4];
#pragma unroll
  for (int i = 0; i < 4; ++i) {
    mean[i] = sum[i] * (1.0f / 128.0f);
    float var = sq[i] * (1.0f / 128.0f) - mean[i] * mean[i];
    rstd[i] = rsqrtf(var + 1e-5f);
  }
#pragma unroll
  for (int t = 0; t < 8; ++t) {
    int col = t * 16 + c;
    float gv = ldf(gw_, col, bf), bv = ldf(bw_, col, bf);
#pragma unroll
    for (int i = 0; i < 4; ++i) {
      float v = (acc[t][i] - mean[i]) * rstd[i] * gv + bv;
      v = v > 0.f ? v : 0.f;
      outf[(long)(m0 + q * 4 + i) * DIM + col] = v;
    }
  }
}

// ---------- fused heterogeneous launches ----------
// K1: b<256 -> Wvm/Wc prep ; then even -> e-count scatter ; odd -> gemm1
__global__ __launch_bounds__(256) void k1_prep_ecount_gemm1(
    const int4* __restrict__ vi, const int4* __restrict__ ei,
    int* __restrict__ cnt_e, int* __restrict__ adj_e,
    const void* __restrict__ X, const unsigned short* __restrict__ Wtvb,
    const float* __restrict__ btvf, unsigned short* __restrict__ Xp_b,
    const void* __restrict__ Wvm, const void* __restrict__ Wte,
    const void* __restrict__ Wem, const void* __restrict__ bte,
    const void* __restrict__ bem, unsigned short* __restrict__ Wvmb,
    unsigned short* __restrict__ Wcb, float* __restrict__ bcf,
    const int* __restrict__ flagp) {
  int b = blockIdx.x;
  if (b < 256) {
    prep_wc_body(b, Wvm, Wte, Wem, bte, bem, Wvmb, Wcb, bcf, *flagp);
    return;
  }
  int b2 = b - 256;
  if (b2 & 1)
    gemm1_body(b2 >> 1, X, Wtvb, btvf, Xp_b, NVERT, *flagp);
  else
    ecount_body(vi, ei, cnt_e, adj_e, b2 >> 1);
}

// K2: %3==0 -> v-count cap-scatter (atomic-bound) ; else -> seg1 (gather-bound)
__global__ __launch_bounds__(256) void k2_vcount_seg1(
    const int4* __restrict__ vi, const int4* __restrict__ ei,
    int* __restrict__ cnt_v, unsigned short* __restrict__ adj_v,
    const int* __restrict__ cnt_e, const int* __restrict__ adj_e,
    const unsigned short* __restrict__ Xp_b, unsigned short* __restrict__ msg_e) {
  int r = blockIdx.x % 3, q = blockIdx.x / 3;
  if (r == 0)
    vcount_body(vi, ei, cnt_v, adj_v, q);
  else
    seg_body<int, CAP_E>(cnt_e, adj_e, Xp_b, msg_e, NEDGE, NVERT,
                         q * 2 + (r - 1));
}

// K3: gemm2 (Ym = concat(Y, msg_e) @ Wc^T + bc ; Yo = relu(LN(Ym)) in-place)
__global__ __launch_bounds__(256) void k3_gemm2(
    const void* __restrict__ Y, const unsigned short* __restrict__ msg_e,
    const unsigned short* __restrict__ Wcb, const float* __restrict__ bcf,
    unsigned short* __restrict__ Ym_b, float* __restrict__ Yo,
    const void* __restrict__ g_e, const void* __restrict__ be_e,
    const int* __restrict__ flagp) {
  gemm23_body<true>(blockIdx.x, 0, NEDGE, Y, msg_e, Wcb, bcf, Ym_b, Yo,
                    g_e, be_e, *flagp);
}

// K4a: seg2 half0 (vertex segs [0, 50000))
__global__ __launch_bounds__(256) void k4a_seg2(
    const int* __restrict__ cnt_v, const unsigned short* __restrict__ adj_v,
    const unsigned short* __restrict__ Ym_b, unsigned short* __restrict__ msg_v) {
  seg_body<unsigned short, CAP_V>(cnt_v, adj_v, Ym_b, msg_v, NVERT, NEDGE,
                                  blockIdx.x);
}

// K4b: %5==4 -> gemm3 half0 (rows [0,50000)) ; else -> seg2 half1 ([50000,100000))
__global__ __launch_bounds__(256) void k4b_seg2_gemm3(
    const int* __restrict__ cnt_v, const unsigned short* __restrict__ adj_v,
    const unsigned short* __restrict__ Ym_b, unsigned short* __restrict__ msg_v,
    const void* __restrict__ X, const unsigned short* __restrict__ Wvmb,
    const float* __restrict__ bvmf, float* __restrict__ Xo,
    const void* __restrict__ g_v, const void* __restrict__ be_v,
    const int* __restrict__ flagp) {
  int r = blockIdx.x % 5, q = blockIdx.x / 5;
  if (r == 4)
    gemm23_body<false>(q, 0, NVERT / 2, X, msg_v, Wvmb, bvmf, nullptr, Xo,
                       g_v, be_v, *flagp);
  else
    seg_body<unsigned short, CAP_V>(cnt_v, adj_v, Ym_b, msg_v, NVERT, NEDGE,
                                    3125 + q * 4 + r);
}

// K5: gemm3 half1 (rows [50000,100000))
__global__ __launch_bounds__(256) void k5_gemm3(
    const void* __restrict__ X, const unsigned short* __restrict__ msg_v,
    const unsigned short* __restrict__ Wvmb, const float* __restrict__ bvmf,
    float* __restrict__ Xo, const void* __restrict__ g_v,
    const void* __restrict__ be_v, const int* __restrict__ flagp) {
  gemm23_body<false>(blockIdx.x, NVERT / 2, NVERT, X, msg_v, Wvmb, bvmf,
                     nullptr, Xo, g_v, be_v, *flagp);
}

extern "C" void kernel_launch(void* const* d_in, const int* in_sizes, int n_in,
                              void* d_out, int out_size, void* d_ws, size_t ws_size,
                              hipStream_t stream) {
  const void* X    = d_in[0];
  const void* Y    = d_in[1];
  const int*  v_idx = (const int*)d_in[2];
  const int*  e_idx = (const int*)d_in[3];
  const void* W_tv = d_in[4];
  const void* b_tv = d_in[5];
  const void* W_te = d_in[6];
  const void* b_te = d_in[7];
  const void* W_em = d_in[8];
  const void* b_em = d_in[9];
  const void* W_vm = d_in[10];
  const void* b_vm = d_in[11];
  const void* g_v  = d_in[12];
  const void* be_v = d_in[13];
  const void* g_e  = d_in[14];
  const void* be_e = d_in[15];

  // d_out (76.8 MB) liveness packing (msg rows = bf16 in first 256B of 512B slots,
  // row-aligned with the f32 outputs that overwrite them in place):
  //  K1:  Xp_b(bf16) [0,25.6M) ; adj_e [25.6,44.8M)
  //  K2:  msg_e(strided bf16) [51.2,76.8M) ; adj_v cap-table in ws
  //  K3:  Yo(f32) [51.2,76.8M) in-place over msg_e (same-row aliasing only)
  //  K4a: msg_v rows [0,50k) -> bytes [0,25.6M) over dead Xp
  //  K4b: seg half1 -> bytes [25.6,51.2M) over dead adj_e ; gemm3 half0 writes
  //       Xo rows [0,50k) in-place over its own msg rows
  //  K5:  Xo rows [50k,100k) in-place
  unsigned short* Xp_b  = (unsigned short*)d_out;
  int*   adj_e = (int*)((char*)d_out + 25600000);   // 50000*96*4 = 19.2 MB
  unsigned short* msg_e = (unsigned short*)((char*)d_out + 51200000);
  float* Yo    = (float*)((char*)d_out + 51200000);
  unsigned short* msg_v = (unsigned short*)d_out;
  float* Xo    = (float*)d_out;

  // ws ~25 MB
  char* p = (char*)d_ws;
  auto alloc = [&](size_t n) { char* r = p; p += (n + 255) & ~(size_t)255; return r; };
  int*   flag  = (int*)alloc(4);
  float* btv_f = (float*)alloc(DIM * 4);
  float* bvm_f = (float*)alloc(DIM * 4);
  float* bc_f  = (float*)alloc(DIM * 4);
  unsigned short* Wtv_b = (unsigned short*)alloc(DIM * DIM * 2);
  unsigned short* Wvm_b = (unsigned short*)alloc(2 * DIM * DIM * 2);
  unsigned short* Wc_b  = (unsigned short*)alloc(2 * DIM * DIM * 2);
  unsigned short* Ym_b  = (unsigned short*)alloc((long)NEDGE * DIM * 2);  // 12.8 MB
  int* cnt_e  = (int*)alloc(NEDGE * 4);
  int* cnt_v  = (int*)alloc(NVERT * 4);
  unsigned short* adj_v = (unsigned short*)alloc((long)NVERT * CAP_V * 2);  // 11.2 MB

  // ---- prep0: flag + btv/bvm + W_tv + zero counters ----
  prep0<<<65 + (NEDGE + NVERT + 255) / 256, 256, 0, stream>>>(
      (const unsigned short*)X, b_tv, b_vm, W_tv, btv_f, bvm_f, Wtv_b, flag,
      cnt_e, cnt_v);

  // ---- K1: Wvm/Wc prep || e-count+adj_e scatter || gemm1 ----
  k1_prep_ecount_gemm1<<<256 + 2 * NB_QTR, 256, 0, stream>>>(
      (const int4*)v_idx, (const int4*)e_idx, cnt_e, adj_e,
      X, Wtv_b, btv_f, Xp_b,
      W_vm, W_te, W_em, b_te, b_em, Wvm_b, Wc_b, bc_f, flag);

  // ---- K2: v-count cap-scatter || seg1 (msg_e = seg_mean(Xp[v] by e), bf16) ----
  k2_vcount_seg1<<<3 * NB_QTR, 256, 0, stream>>>(
      (const int4*)v_idx, (const int4*)e_idx, cnt_v, adj_v,
      cnt_e, adj_e, Xp_b, msg_e);

  // ---- K3: gemm2 (Ym/Yo) ----
  k3_gemm2<<<NB_G23, 256, 0, stream>>>(
      Y, msg_e, Wc_b, bc_f, Ym_b, Yo, g_e, be_e, flag);

  // ---- K4a: seg2 half0 ----
  k4a_seg2<<<3125, 256, 0, stream>>>(cnt_v, adj_v, Ym_b, msg_v);

  // ---- K4b: seg2 half1 || gemm3 half0 ----
  k4b_seg2_gemm3<<<5 * NB_G23, 256, 0, stream>>>(
      cnt_v, adj_v, Ym_b, msg_v, X, Wvm_b, bvm_f, Xo, g_v, be_v, flag);

  // ---- K5: gemm3 half1 ----
  k5_gemm3<<<NB_G23, 256, 0, stream>>>(
      X, msg_v, Wvm_b, bvm_f, Xo, g_v, be_v, flag);
}